// Round 11
// baseline (1273.302 us; speedup 1.0000x reference)
//
#include <hip/hip_runtime.h>
#include <hip/hip_bf16.h>
#include <math.h>

// Problem constants (from reference)
#define N_TOK 4096
#define DIM   2048
#define HID   8192
#define NE    8
#define CAP   2560   // int(1.25 * 4096 / 2)

// GEMM tile: 128x128, BK=32, double-buffered LDS (2 x 16KB = 32KB total, same as BK=64 single)
#define BM 128
#define BN 128
#define BK 32

typedef __attribute__((ext_vector_type(4))) float f32x4;
typedef __attribute__((ext_vector_type(8))) short s16x8;

__device__ __forceinline__ unsigned short f2bf(float f) {
  unsigned int u = __builtin_bit_cast(unsigned int, f);
  u += 0x7fffu + ((u >> 16) & 1u);   // RNE
  return (unsigned short)(u >> 16);
}

__device__ __forceinline__ void async16(const void* g, void* l) {
  __builtin_amdgcn_global_load_lds(
      (const __attribute__((address_space(1))) unsigned int*)g,
      (__attribute__((address_space(3))) unsigned int*)l, 16, 0, 0);
}

// Fast erf-based gelu: A&S 7.1.26 (|eps|<=1.5e-7 abs in erf -> ~1e-6 in gelu,
// far below bf16 rounding 4e-3).
__device__ __forceinline__ float gelu_f(float v) {
  float z = v * 0.70710678118f;
  float az = fabsf(z);
  float t = __builtin_amdgcn_rcpf(1.0f + 0.3275911f * az);
  float p = ((((1.061405429f * t - 1.453152027f) * t + 1.421413741f) * t
              - 0.284496736f) * t + 0.254829592f) * t;
  float ex = __expf(-z * z);
  float erfa = 1.0f - p * ex;
  float erfz = copysignf(erfa, z);
  return 0.5f * v * (1.0f + erfz);
}

// ---------------- transpose + convert: in[R][C] fp32 -> out[C][R] bf16 (64x64 tiles) ----------------
__global__ __launch_bounds__(256) void k_transpose64(const float* __restrict__ in,
                                                     unsigned short* __restrict__ out,
                                                     int R, int C, long inStr, long outStr) {
  __shared__ unsigned short tile[64][66];
  const float* ip = in + (long)blockIdx.z * inStr;
  unsigned short* op = out + (long)blockIdx.z * outStr;
  int c0 = blockIdx.x * 64, r0 = blockIdx.y * 64;
  int t = threadIdx.x;
  {
    int lr = t >> 4, lc = (t & 15) * 4;
#pragma unroll
    for (int p = 0; p < 4; ++p) {
      int row = lr + p * 16;
      float4 v = *(const float4*)(ip + (long)(r0 + row) * C + c0 + lc);
      ushort2 o0; o0.x = f2bf(v.x); o0.y = f2bf(v.y);
      ushort2 o1; o1.x = f2bf(v.z); o1.y = f2bf(v.w);
      *(ushort2*)&tile[row][lc] = o0;
      *(ushort2*)&tile[row][lc + 2] = o1;
    }
  }
  __syncthreads();
  {
    int orr = (t & 15) * 4, oc = t >> 4;
#pragma unroll
    for (int q = 0; q < 4; ++q) {
      int col = oc + q * 16;
      ushort4 o;
      o.x = tile[orr][col]; o.y = tile[orr + 1][col];
      o.z = tile[orr + 2][col]; o.w = tile[orr + 3][col];
      *(ushort4*)(op + (long)(c0 + col) * R + r0 + orr) = o;
    }
  }
}

// ---------------- router ----------------
__global__ __launch_bounds__(256) void k_router(const float* __restrict__ x,
                                                const float* __restrict__ rw,
                                                const float* __restrict__ rb,
                                                int* __restrict__ eidx,
                                                float* __restrict__ ew,
                                                float* __restrict__ imp) {
  __shared__ float simp[NE];
  int tid = threadIdx.x, lane = tid & 63, wv = tid >> 6;
  if (tid < NE) simp[tid] = 0.f;
  __syncthreads();
  int t = blockIdx.x * 4 + wv;   // one wave per token
  float acc[NE] = {};
  const float* xr = x + (long)t * DIM;
  for (int i = 0; i < DIM / 64; ++i) {
    int k = i * 64 + lane;
    float xv = xr[k];
    const float4* wr4 = (const float4*)(rw + (long)k * NE);
    float4 w0 = wr4[0], w1v = wr4[1];
    acc[0] += xv * w0.x;  acc[1] += xv * w0.y;  acc[2] += xv * w0.z;  acc[3] += xv * w0.w;
    acc[4] += xv * w1v.x; acc[5] += xv * w1v.y; acc[6] += xv * w1v.z; acc[7] += xv * w1v.w;
  }
#pragma unroll
  for (int e = 0; e < NE; e++) {
#pragma unroll
    for (int off = 32; off >= 1; off >>= 1) acc[e] += __shfl_down(acc[e], off);
  }
  if (lane == 0) {
    float l[NE], p[NE];
    float mx = -1e30f;
#pragma unroll
    for (int e = 0; e < NE; e++) { l[e] = acc[e] + rb[e]; mx = fmaxf(mx, l[e]); }
    float s = 0.f;
#pragma unroll
    for (int e = 0; e < NE; e++) { p[e] = expf(l[e] - mx); s += p[e]; }
    float inv = 1.f / s;
#pragma unroll
    for (int e = 0; e < NE; e++) p[e] *= inv;
    int a0 = 0;
#pragma unroll
    for (int e = 1; e < NE; e++) if (p[e] > p[a0]) a0 = e;
    int a1 = (a0 == 0) ? 1 : 0;
#pragma unroll
    for (int e = 0; e < NE; e++) if (e != a0 && p[e] > p[a1]) a1 = e;
    eidx[t * 2] = a0; eidx[t * 2 + 1] = a1;
    ew[t * 2] = p[a0]; ew[t * 2 + 1] = p[a1];
#pragma unroll
    for (int e = 0; e < NE; e++) atomicAdd(&simp[e], p[e]);
  }
  __syncthreads();
  if (tid < NE) atomicAdd(&imp[tid], simp[tid]);
}

// ---------------- per-expert ordered capacity assignment ----------------
__global__ void k_build(const int* __restrict__ eidx, const float* __restrict__ ew,
                        int* __restrict__ idxc, float* __restrict__ wg,
                        int* __restrict__ cnt_raw, int* __restrict__ cnt_cap) {
  int e = blockIdx.x;
  int lane = threadIdx.x;
  int base = 0;
  for (int t0 = 0; t0 < N_TOK; t0 += 64) {
    int t = t0 + lane;
    int e0 = eidx[t * 2], e1 = eidx[t * 2 + 1];
    bool sel = (e0 == e) || (e1 == e);
    unsigned long long m = __ballot(sel);
    if (sel) {
      int r = base + __popcll(m & ((1ull << lane) - 1ull));
      if (r < CAP) {
        idxc[e * CAP + r] = t;
        wg[e * CAP + r] = (e0 == e) ? ew[t * 2] : ew[t * 2 + 1];
      }
    }
    base += __popcll(m);
  }
  if (lane == 0) { cnt_raw[e] = base; cnt_cap[e] = base < CAP ? base : CAP; }
}

// ---------------- fused gather + fp32->bf16 convert of selected rows ----------------
__global__ __launch_bounds__(256) void k_gatherf(const float* __restrict__ x,
                                                 const int* __restrict__ idxc,
                                                 const int* __restrict__ cnt_cap,
                                                 unsigned short* __restrict__ xg) {
  int row = blockIdx.x;
  if ((row % CAP) >= cnt_cap[row / CAP]) return;   // invalid slots w=0-gated downstream
  int tok = idxc[row];
  const float* s = x + (long)tok * DIM;
  unsigned short* d = xg + (long)row * DIM;
  int c = threadIdx.x * 8;
  float4 a = *(const float4*)(s + c);
  float4 b = *(const float4*)(s + c + 4);
  ushort4 o0; o0.x = f2bf(a.x); o0.y = f2bf(a.y); o0.z = f2bf(a.z); o0.w = f2bf(a.w);
  ushort4 o1; o1.x = f2bf(b.x); o1.y = f2bf(b.y); o1.z = f2bf(b.z); o1.w = f2bf(b.w);
  *(ushort4*)(d + c) = o0;
  *(ushort4*)(d + c + 4) = o1;
}

// ---------------- grouped GEMM, A[M,K] x B^T[N,K] ----------------------------------------------
// BK=32 double-buffered pipeline (T3 minimum recipe, occupancy-preserving):
//   stage(T+1) -> buf^1 issued at TOP of tile T; compute tile T from buf; one
//   __syncthreads per tile (its vmcnt(0) drain lands after ~600cy of ds_read+MFMA).
//   LDS 2x(8+8)KB = 32KB total == old BK=64 single buffer -> residency unchanged
//   (r5's 64KB dbuf killed occupancy; this keeps it).
// Swizzle (64B rows): phys = row*64 + (kb ^ ((row&3)<<4)); gload_lds dest linear,
// SOURCE inverse-swizzled, ds_read same XOR (rule #21). Residual 4-way read
// conflict (4 slots per row, padding impossible with gload_lds per m104) -- on
// the LDS pipe only, below the MFMA floor.
// + T1 XCD chunking + slab-4 L2 walk (r10). EPI=1: gelu->bf16; EPI=2: atomic combine.
template <int EPI>
__global__ __launch_bounds__(256, 4) void k_gemm(
    const unsigned short* __restrict__ Abase, long Astr,
    const unsigned short* __restrict__ Bbase, long Bstr,
    const float* __restrict__ biasBase, int biasStr,
    void* outBase, long outStr,
    const int* __restrict__ cnt_cap,
    const int* __restrict__ idxc, const float* __restrict__ wgv,
    int K, int Nout, int e_base) {
  // T1 chunk + slab decode (requires gridDim.y % 4 == 0: 64 and 16 both ok)
  int gx = gridDim.x, gy = gridDim.y;
  int nwg = gx * gy * gridDim.z;
  int bid = blockIdx.x + gx * (blockIdx.y + gy * blockIdx.z);
  int chunk = nwg >> 3;
  int nbid = (bid & 7) * chunk + (bid >> 3);
  int bz = nbid / (gx * gy);
  int gl = nbid % (gx * gy);
  int byg = gl / (gx * 4);
  int rr = gl % (gx * 4);
  int bx = rr >> 2;                 // bx outer within slab
  int by = byg * 4 + (rr & 3);      // byo innermost

  int e = e_base + bz;
  int cnt = cnt_cap[e];
  int m0 = bx * BM;
  if (m0 >= cnt) return;                 // data-dependent early exit
  int n0 = by * BN;
  const unsigned short* A = Abase + (long)e * Astr;
  const unsigned short* B = Bbase + (long)e * Bstr;
  __shared__ unsigned short Als[2][BM * BK];
  __shared__ unsigned short Bls[2][BN * BK];
  int tid = threadIdx.x, lane = tid & 63;
  int wv = tid >> 6, wr = wv >> 1, wc = wv & 1;   // 2x2 waves, 64x64 out each
  f32x4 acc[4][4] = {};

  auto stage = [&](int T) {
    int p = T & 1;
    int kt = T * BK;
#pragma unroll
    for (int s = 0; s < 2; s++) {       // A tile: 128x32 bf16 = 8KB = 512 x 16B chunks
      int c = s * 256 + tid;
      int row = c >> 2, k16 = c & 3;
      int sk = k16 ^ (row & 3);         // inverse-swizzled source chunk
      async16(A + (long)(m0 + row) * K + kt + sk * 8, (char*)Als[p] + c * 16);
    }
#pragma unroll
    for (int s = 0; s < 2; s++) {       // B tile
      int c = s * 256 + tid;
      int row = c >> 2, k16 = c & 3;
      int sk = k16 ^ (row & 3);
      async16(B + (long)(n0 + row) * K + kt + sk * 8, (char*)Bls[p] + c * 16);
    }
  };

  int NT = K / BK;
  stage(0);
  __syncthreads();                       // tile 0 resident

  for (int T = 0; T < NT; ++T) {
    if (T + 1 < NT) stage(T + 1);        // issue early: latency hides under compute below
    asm volatile("" ::: "memory");       // keep issue order: stages before ds_reads
    const char* Ab = (const char*)Als[T & 1];
    const char* Bb = (const char*)Bls[T & 1];
    s16x8 af[4], bfr[4];
    int kb = (lane >> 4) * 16;           // byte offset within 64B row
#pragma unroll
    for (int t4 = 0; t4 < 4; t4++) {
      int ar = wr * 64 + t4 * 16 + (lane & 15);
      int br = wc * 64 + t4 * 16 + (lane & 15);
      af[t4]  = *(const s16x8*)(Ab + ar * 64 + (kb ^ ((ar & 3) << 4)));
      bfr[t4] = *(const s16x8*)(Bb + br * 64 + (kb ^ ((br & 3) << 4)));
    }
#pragma unroll
    for (int i = 0; i < 4; i++)
#pragma unroll
      for (int j = 0; j < 4; j++)
        acc[i][j] = __builtin_amdgcn_mfma_f32_16x16x32_bf16(af[i], bfr[j], acc[i][j], 0, 0, 0);
    __syncthreads();                     // drains vmcnt(0) for stage(T+1): issued ~600cy ago
  }

  const float* bias = biasBase + (long)e * biasStr;
  if constexpr (EPI == 1) {
    unsigned short* hout = (unsigned short*)outBase + (long)e * outStr;
#pragma unroll
    for (int j = 0; j < 4; j++) {
      int col = n0 + wc * 64 + j * 16 + (lane & 15);
      float bv = bias[col];
#pragma unroll
      for (int i = 0; i < 4; i++) {
        int rb0 = m0 + wr * 64 + i * 16 + (lane >> 4) * 4;
#pragma unroll
        for (int r = 0; r < 4; r++) {
          float v = acc[i][j][r] + bv;
          hout[(long)(rb0 + r) * Nout + col] = f2bf(gelu_f(v));
        }
      }
    }
  } else {
    float* fin = (float*)outBase;
#pragma unroll
    for (int i = 0; i < 4; i++) {
      int rb0 = m0 + wr * 64 + i * 16 + (lane >> 4) * 4;
      float4 w4 = *(const float4*)(wgv + e * CAP + rb0);   // rb0 is 4-aligned
      int4 t4v = *(const int4*)(idxc + e * CAP + rb0);
      float wa[4] = {w4.x, w4.y, w4.z, w4.w};
      int ta[4] = {t4v.x, t4v.y, t4v.z, t4v.w};
#pragma unroll
      for (int r = 0; r < 4; r++) {
        float w = wa[r];
        if (w != 0.f) {
          int tok = ta[r];
#pragma unroll
          for (int j = 0; j < 4; j++) {
            int col = n0 + wc * 64 + j * 16 + (lane & 15);
            float v = (acc[i][j][r] + bias[col]) * w;
            atomicAdd(fin + (long)tok * Nout + col, v);
          }
        }
      }
    }
  }
}

// ---------------- aux loss ----------------
__global__ void k_aux(const float* __restrict__ imp, const int* __restrict__ cnt,
                      float* __restrict__ out) {
  if (threadIdx.x == 0) {
    float bal = 0.f, il = 0.f;
    for (int e = 0; e < NE; e++) {
      bal += (imp[e] / (float)N_TOK) * ((float)cnt[e] / (float)N_TOK);
      il += imp[e] * imp[e];
    }
    out[0] = bal * (float)NE + il / (float)NE;
  }
}

extern "C" void kernel_launch(void* const* d_in, const int* in_sizes, int n_in,
                              void* d_out, int out_size, void* d_ws, size_t ws_size,
                              hipStream_t stream) {
  const float* x  = (const float*)d_in[0];
  const float* rw = (const float*)d_in[1];
  const float* rb = (const float*)d_in[2];
  const float* w1 = (const float*)d_in[3];
  const float* b1 = (const float*)d_in[4];
  const float* w2 = (const float*)d_in[5];
  const float* b2 = (const float*)d_in[6];
  float* out = (float*)d_out;

  char* ws = (char*)d_ws;
  size_t off = 0;
  auto alloc = [&](size_t bytes) -> char* {
    char* p = ws + off;
    off = (off + bytes + 255) & ~(size_t)255;
    return p;
  };
  float* imp     = (float*)alloc(NE * 4);
  int*   cnt_raw = (int*)alloc(NE * 4);
  int*   cnt_cap = (int*)alloc(NE * 4);
  int*   idxc    = (int*)alloc((size_t)NE * CAP * 4);
  float* wg      = (float*)alloc((size_t)NE * CAP * 4);
  int*   eidx    = (int*)alloc((size_t)N_TOK * 2 * 4);
  float* ew      = (float*)alloc((size_t)N_TOK * 2 * 4);
  size_t ctrl_end = off;
  unsigned short* xg = (unsigned short*)alloc((size_t)NE * CAP * DIM * 2);

  size_t need_grouped = off + (size_t)NE * DIM * HID * 2 * 2     // w1t + w2t
                            + (size_t)NE * CAP * HID * 2 + 4096; // h
  bool grouped = ws_size >= need_grouped;

  unsigned short *w1t, *w2t, *hbuf;
  if (grouped) {
    w1t  = (unsigned short*)alloc((size_t)NE * DIM * HID * 2);
    w2t  = (unsigned short*)alloc((size_t)NE * HID * DIM * 2);
    hbuf = (unsigned short*)alloc((size_t)NE * CAP * HID * 2);
  } else {
    w1t  = (unsigned short*)alloc((size_t)DIM * HID * 2);
    w2t  = (unsigned short*)alloc((size_t)HID * DIM * 2);
    hbuf = (unsigned short*)alloc((size_t)CAP * HID * 2);
  }

  hipMemsetAsync(d_out, 0, ((size_t)N_TOK * DIM + 1) * 4, stream);
  hipMemsetAsync(d_ws, 0, ctrl_end, stream);

  k_router<<<N_TOK / 4, 256, 0, stream>>>(x, rw, rb, eidx, ew, imp);
  k_build<<<NE, 64, 0, stream>>>(eidx, ew, idxc, wg, cnt_raw, cnt_cap);
  k_gatherf<<<NE * CAP, 256, 0, stream>>>(x, idxc, cnt_cap, xg);

  if (grouped) {
    k_transpose64<<<dim3(HID / 64, DIM / 64, NE), 256, 0, stream>>>(
        w1, w1t, DIM, HID, (long)DIM * HID, (long)DIM * HID);
    k_transpose64<<<dim3(DIM / 64, HID / 64, NE), 256, 0, stream>>>(
        w2, w2t, HID, DIM, (long)HID * DIM, (long)HID * DIM);
    k_gemm<1><<<dim3(CAP / BM, HID / BN, NE), 256, 0, stream>>>(
        xg, (long)CAP * DIM, w1t, (long)HID * DIM, b1, HID,
        hbuf, (long)CAP * HID, cnt_cap, nullptr, nullptr, DIM, HID, 0);
    k_gemm<2><<<dim3(CAP / BM, DIM / BN, NE), 256, 0, stream>>>(
        hbuf, (long)CAP * HID, w2t, (long)DIM * HID, b2, DIM,
        d_out, 0, cnt_cap, idxc, wg, HID, DIM, 0);
  } else {
    for (int e = 0; e < NE; e++) {
      k_transpose64<<<dim3(HID / 64, DIM / 64, 1), 256, 0, stream>>>(
          w1 + (long)e * DIM * HID, w1t, DIM, HID, 0, 0);
      k_gemm<1><<<dim3(CAP / BM, HID / BN, 1), 256, 0, stream>>>(
          xg, (long)CAP * DIM, w1t, 0, b1, HID,
          hbuf, 0, cnt_cap, nullptr, nullptr, DIM, HID, e);
      k_transpose64<<<dim3(DIM / 64, HID / 64, 1), 256, 0, stream>>>(
          w2 + (long)e * HID * DIM, w2t, HID, DIM, 0, 0);
      k_gemm<2><<<dim3(CAP / BM, DIM / BN, 1), 256, 0, stream>>>(
          hbuf, 0, w2t, 0, b2, DIM,
          d_out, 0, cnt_cap, idxc, wg, HID, DIM, e);
    }
  }
  k_aux<<<1, 64, 0, stream>>>(imp, cnt_raw, out + (size_t)N_TOK * DIM);
}

// Round 12
// 1099.590 us; speedup vs baseline: 1.1580x; 1.1580x over previous
//
#include <hip/hip_runtime.h>
#include <hip/hip_bf16.h>
#include <math.h>

// Problem constants (from reference)
#define N_TOK 4096
#define DIM   2048
#define HID   8192
#define NE    8
#define CAP   2560   // int(1.25 * 4096 / 2)

// GEMM tile (r10 structure: 128x128, BK=64, 4 waves, 2-barrier, best measured)
#define BM 128
#define BN 128
#define BK 64

typedef __attribute__((ext_vector_type(4))) float f32x4;
typedef __attribute__((ext_vector_type(8))) short s16x8;

__device__ __forceinline__ unsigned short f2bf(float f) {
  unsigned int u = __builtin_bit_cast(unsigned int, f);
  u += 0x7fffu + ((u >> 16) & 1u);   // RNE
  return (unsigned short)(u >> 16);
}

__device__ __forceinline__ void async16(const void* g, void* l) {
  __builtin_amdgcn_global_load_lds(
      (const __attribute__((address_space(1))) unsigned int*)g,
      (__attribute__((address_space(3))) unsigned int*)l, 16, 0, 0);
}

// Fast erf-based gelu: A&S 7.1.26 (|eps|<=1.5e-7 in erf -> ~1e-6 in gelu, << bf16 4e-3)
__device__ __forceinline__ float gelu_f(float v) {
  float z = v * 0.70710678118f;
  float az = fabsf(z);
  float t = __builtin_amdgcn_rcpf(1.0f + 0.3275911f * az);
  float p = ((((1.061405429f * t - 1.453152027f) * t + 1.421413741f) * t
              - 0.284496736f) * t + 0.254829592f) * t;
  float ex = __expf(-z * z);
  float erfa = 1.0f - p * ex;
  float erfz = copysignf(erfa, z);
  return 0.5f * v * (1.0f + erfz);
}

// ---------------- transpose body: ip[R][C] fp32 -> op[C][R] bf16, one 64x64 tile ----------------
__device__ __forceinline__ void transpose_body(char* smem, int bx, int by,
                                               const float* __restrict__ ip,
                                               unsigned short* __restrict__ op,
                                               int R, int C) {
  auto tile = (unsigned short(*)[66])smem;
  int c0 = bx * 64, r0 = by * 64;
  int t = threadIdx.x;
  {
    int lr = t >> 4, lc = (t & 15) * 4;
#pragma unroll
    for (int p = 0; p < 4; ++p) {
      int row = lr + p * 16;
      float4 v = *(const float4*)(ip + (long)(r0 + row) * C + c0 + lc);
      ushort2 o0; o0.x = f2bf(v.x); o0.y = f2bf(v.y);
      ushort2 o1; o1.x = f2bf(v.z); o1.y = f2bf(v.w);
      *(ushort2*)&tile[row][lc] = o0;
      *(ushort2*)&tile[row][lc + 2] = o1;
    }
  }
  __syncthreads();
  {
    int orr = (t & 15) * 4, oc = t >> 4;
#pragma unroll
    for (int q = 0; q < 4; ++q) {
      int col = oc + q * 16;
      ushort4 o;
      o.x = tile[orr][col]; o.y = tile[orr + 1][col];
      o.z = tile[orr + 2][col]; o.w = tile[orr + 3][col];
      *(ushort4*)(op + (long)(c0 + col) * R + r0 + orr) = o;
    }
  }
}

// standalone transpose kernel (fallback path)
__global__ __launch_bounds__(256) void k_transpose64(const float* __restrict__ in,
                                                     unsigned short* __restrict__ out,
                                                     int R, int C, long inStr, long outStr) {
  __shared__ __align__(16) char smem[8448];
  transpose_body(smem, blockIdx.x, blockIdx.y,
                 in + (long)blockIdx.z * inStr, out + (long)blockIdx.z * outStr, R, C);
}

// ---------------- router ----------------
__global__ __launch_bounds__(256) void k_router(const float* __restrict__ x,
                                                const float* __restrict__ rw,
                                                const float* __restrict__ rb,
                                                int* __restrict__ eidx,
                                                float* __restrict__ ew,
                                                float* __restrict__ imp) {
  __shared__ float simp[NE];
  int tid = threadIdx.x, lane = tid & 63, wv = tid >> 6;
  if (tid < NE) simp[tid] = 0.f;
  __syncthreads();
  int t = blockIdx.x * 4 + wv;   // one wave per token
  float acc[NE] = {};
  const float* xr = x + (long)t * DIM;
  for (int i = 0; i < DIM / 64; ++i) {
    int k = i * 64 + lane;
    float xv = xr[k];
    const float4* wr4 = (const float4*)(rw + (long)k * NE);
    float4 w0 = wr4[0], w1v = wr4[1];
    acc[0] += xv * w0.x;  acc[1] += xv * w0.y;  acc[2] += xv * w0.z;  acc[3] += xv * w0.w;
    acc[4] += xv * w1v.x; acc[5] += xv * w1v.y; acc[6] += xv * w1v.z; acc[7] += xv * w1v.w;
  }
#pragma unroll
  for (int e = 0; e < NE; e++) {
#pragma unroll
    for (int off = 32; off >= 1; off >>= 1) acc[e] += __shfl_down(acc[e], off);
  }
  if (lane == 0) {
    float l[NE], p[NE];
    float mx = -1e30f;
#pragma unroll
    for (int e = 0; e < NE; e++) { l[e] = acc[e] + rb[e]; mx = fmaxf(mx, l[e]); }
    float s = 0.f;
#pragma unroll
    for (int e = 0; e < NE; e++) { p[e] = expf(l[e] - mx); s += p[e]; }
    float inv = 1.f / s;
#pragma unroll
    for (int e = 0; e < NE; e++) p[e] *= inv;
    int a0 = 0;
#pragma unroll
    for (int e = 1; e < NE; e++) if (p[e] > p[a0]) a0 = e;
    int a1 = (a0 == 0) ? 1 : 0;
#pragma unroll
    for (int e = 0; e < NE; e++) if (e != a0 && p[e] > p[a1]) a1 = e;
    eidx[t * 2] = a0; eidx[t * 2 + 1] = a1;
    ew[t * 2] = p[a0]; ew[t * 2 + 1] = p[a1];
#pragma unroll
    for (int e = 0; e < NE; e++) atomicAdd(&simp[e], p[e]);
  }
  __syncthreads();
  if (tid < NE) atomicAdd(&imp[tid], simp[tid]);
}

// ---------------- per-expert ordered capacity assignment ----------------
__global__ void k_build(const int* __restrict__ eidx, const float* __restrict__ ew,
                        int* __restrict__ idxc, float* __restrict__ wg,
                        int* __restrict__ cnt_raw, int* __restrict__ cnt_cap) {
  int e = blockIdx.x;
  int lane = threadIdx.x;
  int base = 0;
  for (int t0 = 0; t0 < N_TOK; t0 += 64) {
    int t = t0 + lane;
    int e0 = eidx[t * 2], e1 = eidx[t * 2 + 1];
    bool sel = (e0 == e) || (e1 == e);
    unsigned long long m = __ballot(sel);
    if (sel) {
      int r = base + __popcll(m & ((1ull << lane) - 1ull));
      if (r < CAP) {
        idxc[e * CAP + r] = t;
        wg[e * CAP + r] = (e0 == e) ? ew[t * 2] : ew[t * 2 + 1];
      }
    }
    base += __popcll(m);
  }
  if (lane == 0) { cnt_raw[e] = base; cnt_cap[e] = base < CAP ? base : CAP; }
}

// ---------------- gather body (one row per block) ----------------
__device__ __forceinline__ void gather_body(int row, const float* __restrict__ x,
                                            const int* __restrict__ idxc,
                                            const int* __restrict__ cnt_cap,
                                            unsigned short* __restrict__ xg) {
  if ((row % CAP) >= cnt_cap[row / CAP]) return;   // invalid slots w=0-gated downstream
  int tok = idxc[row];
  const float* s = x + (long)tok * DIM;
  unsigned short* d = xg + (long)row * DIM;
  int c = threadIdx.x * 8;
  float4 a = *(const float4*)(s + c);
  float4 b = *(const float4*)(s + c + 4);
  ushort4 o0; o0.x = f2bf(a.x); o0.y = f2bf(a.y); o0.z = f2bf(a.z); o0.w = f2bf(a.w);
  ushort4 o1; o1.x = f2bf(b.x); o1.y = f2bf(b.y); o1.z = f2bf(b.z); o1.w = f2bf(b.w);
  *(ushort4*)(d + c) = o0;
  *(ushort4*)(d + c + 4) = o1;
}

__global__ __launch_bounds__(256) void k_gatherf(const float* __restrict__ x,
                                                 const int* __restrict__ idxc,
                                                 const int* __restrict__ cnt_cap,
                                                 unsigned short* __restrict__ xg) {
  gather_body(blockIdx.x, x, idxc, cnt_cap, xg);
}

// ---------------- grouped GEMM body, A[M,K] x B^T[N,K]  (r10 proven core) -----------------------
// m97 2-barrier loop + T2 swizzle + T1 XCD chunking + slab-4 L2 walk. Grid dims are
// template constants (GX,GY,GZ) so the body works inside fused dispatches.
// LDS: phys_byte(row,colB)=row*128+(colB^((row&7)<<4)); gload_lds dest linear,
// SOURCE inverse-swizzled, ds_read same XOR (rule #21).
// EPI=1: h = gelu(A.Bt + b1) -> bf16   EPI=2: atomicAdd(final[token], (A.Bt + b2)*wg)
template <int EPI, int GX, int GY, int GZ>
__device__ __forceinline__ void gemm_body(char* smem, int bid,
    const unsigned short* __restrict__ Abase, long Astr,
    const unsigned short* __restrict__ Bbase, long Bstr,
    const float* __restrict__ biasBase, int biasStr,
    void* outBase, long outStr,
    const int* __restrict__ cnt_cap,
    const int* __restrict__ idxc, const float* __restrict__ wgv,
    int K, int Nout, int e_base) {
  constexpr int NWG = GX * GY * GZ;
  int chunk = NWG >> 3;
  int nbid = (bid & 7) * chunk + (bid >> 3);
  int bz = nbid / (GX * GY);
  int gl = nbid % (GX * GY);
  int byg = gl / (GX * 4);
  int rr = gl % (GX * 4);
  int bx = rr >> 2;                 // bx outer within slab
  int by = byg * 4 + (rr & 3);      // byo innermost

  int e = e_base + bz;
  int cnt = cnt_cap[e];
  int m0 = bx * BM;
  if (m0 >= cnt) return;                 // data-dependent early exit
  int n0 = by * BN;
  const unsigned short* A = Abase + (long)e * Astr;
  const unsigned short* B = Bbase + (long)e * Bstr;
  unsigned short* Als = (unsigned short*)smem;
  unsigned short* Bls = Als + BM * BK;
  int tid = threadIdx.x, lane = tid & 63;
  int wv = tid >> 6, wr = wv >> 1, wc = wv & 1;   // 2x2 waves, 64x64 out each
  f32x4 acc[4][4] = {};

  for (int kt = 0; kt < K; kt += BK) {
#pragma unroll
    for (int s = 0; s < 4; s++) {       // A tile: 128x64 bf16 = 1024 x 16B chunks
      int c = s * 256 + tid;
      int row = c >> 3, k16 = c & 7;
      int sk = k16 ^ (row & 7);         // inverse-swizzled source chunk
      async16(A + (long)(m0 + row) * K + kt + sk * 8, (char*)Als + c * 16);
    }
#pragma unroll
    for (int s = 0; s < 4; s++) {       // B tile
      int c = s * 256 + tid;
      int row = c >> 3, k16 = c & 7;
      int sk = k16 ^ (row & 7);
      async16(B + (long)(n0 + row) * K + kt + sk * 8, (char*)Bls + c * 16);
    }
    __syncthreads();
#pragma unroll
    for (int kk = 0; kk < 2; kk++) {
      s16x8 af[4], bfr[4];
#pragma unroll
      for (int t4 = 0; t4 < 4; t4++) {
        int ar = wr * 64 + t4 * 16 + (lane & 15);
        int br = wc * 64 + t4 * 16 + (lane & 15);
        int kb = kk * 64 + (lane >> 4) * 16;   // byte offset within row
        af[t4]  = *(const s16x8*)((const char*)Als + ar * 128 + (kb ^ ((ar & 7) << 4)));
        bfr[t4] = *(const s16x8*)((const char*)Bls + br * 128 + (kb ^ ((br & 7) << 4)));
      }
#pragma unroll
      for (int i = 0; i < 4; i++)
#pragma unroll
        for (int j = 0; j < 4; j++)
          acc[i][j] = __builtin_amdgcn_mfma_f32_16x16x32_bf16(af[i], bfr[j], acc[i][j], 0, 0, 0);
    }
    __syncthreads();
  }

  const float* bias = biasBase + (long)e * biasStr;
  if constexpr (EPI == 1) {
    unsigned short* hout = (unsigned short*)outBase + (long)e * outStr;
#pragma unroll
    for (int j = 0; j < 4; j++) {
      int col = n0 + wc * 64 + j * 16 + (lane & 15);
      float bv = bias[col];
#pragma unroll
      for (int i = 0; i < 4; i++) {
        int rb0 = m0 + wr * 64 + i * 16 + (lane >> 4) * 4;
#pragma unroll
        for (int r = 0; r < 4; r++) {
          float v = acc[i][j][r] + bv;
          hout[(long)(rb0 + r) * Nout + col] = f2bf(gelu_f(v));
        }
      }
    }
  } else {
    float* fin = (float*)outBase;
#pragma unroll
    for (int i = 0; i < 4; i++) {
      int rb0 = m0 + wr * 64 + i * 16 + (lane >> 4) * 4;
      float4 w4 = *(const float4*)(wgv + e * CAP + rb0);   // rb0 is 4-aligned
      int4 t4v = *(const int4*)(idxc + e * CAP + rb0);
      float wa[4] = {w4.x, w4.y, w4.z, w4.w};
      int ta[4] = {t4v.x, t4v.y, t4v.z, t4v.w};
#pragma unroll
      for (int r = 0; r < 4; r++) {
        float w = wa[r];
        if (w != 0.f) {
          int tok = ta[r];
#pragma unroll
          for (int j = 0; j < 4; j++) {
            int col = n0 + wc * 64 + j * 16 + (lane & 15);
            float v = (acc[i][j][r] + bias[col]) * w;
            atomicAdd(fin + (long)tok * Nout + col, v);
          }
        }
      }
    }
  }
}

// standalone GEMM kernel (G2 + fallback)
template <int EPI, int GX, int GY, int GZ>
__global__ __launch_bounds__(256, 4) void k_gemm(
    const unsigned short* __restrict__ Abase, long Astr,
    const unsigned short* __restrict__ Bbase, long Bstr,
    const float* __restrict__ biasBase, int biasStr,
    void* outBase, long outStr,
    const int* __restrict__ cnt_cap,
    const int* __restrict__ idxc, const float* __restrict__ wgv,
    int K, int Nout, int e_base) {
  __shared__ __align__(16) char smem[32768];
  int bid = blockIdx.x + GX * (blockIdx.y + GY * blockIdx.z);
  gemm_body<EPI, GX, GY, GZ>(smem, bid, Abase, Astr, Bbase, Bstr, biasBase, biasStr,
                             outBase, outStr, cnt_cap, idxc, wgv, K, Nout, e_base);
}

// ---------------- FUSED: gather + transpose1 (independent work, one dispatch) ----------------
__global__ __launch_bounds__(256) void k_gat1(
    const float* __restrict__ x, const int* __restrict__ idxc,
    const int* __restrict__ cnt_cap, unsigned short* __restrict__ xg,
    const float* __restrict__ w1, unsigned short* __restrict__ w1t) {
  __shared__ __align__(16) char smem[8448];
  int bid = blockIdx.x;
  constexpr int GB = NE * CAP;            // 20480 gather blocks
  if (bid < GB) {
    gather_body(bid, x, idxc, cnt_cap, xg);
  } else {
    int tb = bid - GB;                    // T1: in w1[DIM][HID], grid (HID/64=128, DIM/64=32, NE)
    int bx = tb & 127;
    int by = (tb >> 7) & 31;
    int bz = tb >> 12;
    transpose_body(smem, bx, by, w1 + (long)bz * DIM * HID, w1t + (long)bz * DIM * HID,
                   DIM, HID);
  }
}

// ---------------- FUSED: GEMM1 + transpose2 (T2 fills GEMM1's idle HBM/issue slots) ----------
__global__ __launch_bounds__(256, 4) void k_g1t2(
    const unsigned short* __restrict__ xg, const unsigned short* __restrict__ w1t,
    const float* __restrict__ b1, unsigned short* __restrict__ hbuf,
    const int* __restrict__ cnt_cap,
    const float* __restrict__ w2, unsigned short* __restrict__ w2t) {
  __shared__ __align__(16) char smem[32768];
  int bid = blockIdx.x;
  constexpr int G1B = 20 * 64 * 8;        // GEMM1 blocks first (fill CUs, latency-bound)
  if (bid < G1B) {
    gemm_body<1, 20, 64, 8>(smem, bid, xg, (long)CAP * DIM, w1t, (long)HID * DIM,
                            b1, HID, hbuf, (long)CAP * HID, cnt_cap, nullptr, nullptr,
                            DIM, HID, 0);
  } else {
    int tb = bid - G1B;                   // T2: in w2[HID][DIM], grid (DIM/64=32, HID/64=128, NE)
    int bx = tb & 31;
    int by = (tb >> 5) & 127;
    int bz = tb >> 12;
    transpose_body(smem, bx, by, w2 + (long)bz * HID * DIM, w2t + (long)bz * HID * DIM,
                   HID, DIM);
  }
}

// ---------------- aux loss ----------------
__global__ void k_aux(const float* __restrict__ imp, const int* __restrict__ cnt,
                      float* __restrict__ out) {
  if (threadIdx.x == 0) {
    float bal = 0.f, il = 0.f;
    for (int e = 0; e < NE; e++) {
      bal += (imp[e] / (float)N_TOK) * ((float)cnt[e] / (float)N_TOK);
      il += imp[e] * imp[e];
    }
    out[0] = bal * (float)NE + il / (float)NE;
  }
}

extern "C" void kernel_launch(void* const* d_in, const int* in_sizes, int n_in,
                              void* d_out, int out_size, void* d_ws, size_t ws_size,
                              hipStream_t stream) {
  const float* x  = (const float*)d_in[0];
  const float* rw = (const float*)d_in[1];
  const float* rb = (const float*)d_in[2];
  const float* w1 = (const float*)d_in[3];
  const float* b1 = (const float*)d_in[4];
  const float* w2 = (const float*)d_in[5];
  const float* b2 = (const float*)d_in[6];
  float* out = (float*)d_out;

  char* ws = (char*)d_ws;
  size_t off = 0;
  auto alloc = [&](size_t bytes) -> char* {
    char* p = ws + off;
    off = (off + bytes + 255) & ~(size_t)255;
    return p;
  };
  float* imp     = (float*)alloc(NE * 4);
  int*   cnt_raw = (int*)alloc(NE * 4);
  int*   cnt_cap = (int*)alloc(NE * 4);
  int*   idxc    = (int*)alloc((size_t)NE * CAP * 4);
  float* wg      = (float*)alloc((size_t)NE * CAP * 4);
  int*   eidx    = (int*)alloc((size_t)N_TOK * 2 * 4);
  float* ew      = (float*)alloc((size_t)N_TOK * 2 * 4);
  size_t ctrl_end = off;
  unsigned short* xg = (unsigned short*)alloc((size_t)NE * CAP * DIM * 2);

  size_t need_grouped = off + (size_t)NE * DIM * HID * 2 * 2     // w1t + w2t
                            + (size_t)NE * CAP * HID * 2 + 4096; // h
  bool grouped = ws_size >= need_grouped;

  unsigned short *w1t, *w2t, *hbuf;
  if (grouped) {
    w1t  = (unsigned short*)alloc((size_t)NE * DIM * HID * 2);
    w2t  = (unsigned short*)alloc((size_t)NE * HID * DIM * 2);
    hbuf = (unsigned short*)alloc((size_t)NE * CAP * HID * 2);
  } else {
    w1t  = (unsigned short*)alloc((size_t)DIM * HID * 2);
    w2t  = (unsigned short*)alloc((size_t)HID * DIM * 2);
    hbuf = (unsigned short*)alloc((size_t)CAP * HID * 2);
  }

  hipMemsetAsync(d_out, 0, ((size_t)N_TOK * DIM + 1) * 4, stream);
  hipMemsetAsync(d_ws, 0, ctrl_end, stream);

  k_router<<<N_TOK / 4, 256, 0, stream>>>(x, rw, rb, eidx, ew, imp);
  k_build<<<NE, 64, 0, stream>>>(eidx, ew, idxc, wg, cnt_raw, cnt_cap);

  if (grouped) {
    // gather (20480 blocks) + transpose1 (128*32*8 = 32768 blocks) in one dispatch
    k_gat1<<<NE * CAP + (HID / 64) * (DIM / 64) * NE, 256, 0, stream>>>(
        x, idxc, cnt_cap, xg, w1, w1t);
    // GEMM1 (20*64*8 = 10240 blocks) + transpose2 (32*128*8 = 32768 blocks) in one dispatch
    k_g1t2<<<20 * 64 * 8 + (DIM / 64) * (HID / 64) * NE, 256, 0, stream>>>(
        xg, w1t, b1, hbuf, cnt_cap, w2, w2t);
    k_gemm<2, 16, 16, 8><<<dim3(16, 16, 8), 256, 0, stream>>>(
        hbuf, (long)CAP * HID, w2t, (long)DIM * HID, b2, DIM,
        d_out, 0, cnt_cap, idxc, wg, HID, DIM, 0);
  } else {
    k_gatherf<<<NE * CAP, 256, 0, stream>>>(x, idxc, cnt_cap, xg);
    for (int e = 0; e < NE; e++) {
      k_transpose64<<<dim3(HID / 64, DIM / 64, 1), 256, 0, stream>>>(
          w1 + (long)e * DIM * HID, w1t, DIM, HID, 0, 0);
      k_gemm<1, 20, 64, 1><<<dim3(20, 64, 1), 256, 0, stream>>>(
          xg, (long)CAP * DIM, w1t, 0, b1, HID,
          hbuf, 0, cnt_cap, nullptr, nullptr, DIM, HID, e);
      k_transpose64<<<dim3(DIM / 64, HID / 64, 1), 256, 0, stream>>>(
          w2 + (long)e * HID * DIM, w2t, HID, DIM, 0, 0);
      k_gemm<2, 16, 16, 1><<<dim3(16, 16, 1), 256, 0, stream>>>(
          hbuf, 0, w2t, 0, b2, DIM,
          d_out, 0, cnt_cap, idxc, wg, HID, DIM, e);
    }
  }
  k_aux<<<1, 64, 0, stream>>>(imp, cnt_raw, out + (size_t)N_TOK * DIM);
}